// Round 8
// baseline (57.774 us; speedup 1.0000x reference)
//
#include <hip/hip_runtime.h>
#include <hip/hip_cooperative_groups.h>
#include <stdint.h>
#include <math.h>

// SamplePatches: gumbel top-k sampling (Threefry2x32 counter-mode, key 42) + patch gather.
// Inputs: d_in[0]=x_low (unused), d_in[1]=x_high (unused),
//         d_in[2]=attention [4,64,64] f32, d_in[3]=WSI [4,3,2048,2048] f32.
// Output: patches [4,32,3,128,128] f32 then sampled_attention [4,32] f32, concat flat.
//
// JAX defaults jax_threefry_partitionable=True: bits for element e are
// threefry2x32(key, (hi=0, lo=e)) with the two output words XOR-folded.
//
// Single cooperative kernel: blocks 0..3 sample (per-wave DPP top-32, gallop
// rank-merge; total order = (value desc, j asc) == lax.top_k), grid.sync(),
// then all blocks gather patches. 256 blocks x 1024 thr, VGPR<=128 via
// launch_bounds -> 16 waves/CU -> all blocks co-resident on 256 CUs.

namespace cg = cooperative_groups;

namespace {
constexpr int B      = 4;
constexpr int NP     = 32;     // N_PATCHES
constexpr int PATCH_ = 128;
constexpr int GRID   = 4096;   // 64*64 attention cells per batch
constexpr int HW     = 2048;
constexpr int NT     = 1024;   // threads per block
constexpr int NBLK   = 256;    // cooperative grid size (== CU count)
constexpr int NW     = NT / 64;          // 16 waves per sampling block
constexpr int QP     = GRID / NT;        // 4 scores per thread
constexpr int NCAND  = NW * NP;          // 512 merge candidates
constexpr int TOT4   = B * NP * 3 * PATCH_ * PATCH_ / 4;   // 1,572,864 float4s
constexpr int GITER  = TOT4 / (NBLK * NT);                 // 6 per thread
constexpr float EPSF = 1e-12f;

typedef float f32x4 __attribute__((ext_vector_type(4)));

__device__ inline uint32_t rotl32(uint32_t x, uint32_t r){ return (x<<r)|(x>>(32u-r)); }

// Threefry-2x32 with key (0, 42)  == jax.random.key(42)
__device__ inline void threefry2x32_k042(uint32_t x0, uint32_t x1,
                                         uint32_t& o0, uint32_t& o1){
  const uint32_t k0 = 0u, k1 = 42u;
  const uint32_t k2 = k0 ^ k1 ^ 0x1BD11BDAu;
  x0 += k0; x1 += k1;
#define RND(r) { x0 += x1; x1 = rotl32(x1,(r)); x1 ^= x0; }
#define G_A RND(13) RND(15) RND(26) RND(6)
#define G_B RND(17) RND(29) RND(16) RND(24)
  G_A x0 += k1; x1 += k2 + 1u;
  G_B x0 += k2; x1 += k0 + 2u;
  G_A x0 += k0; x1 += k1 + 3u;
  G_B x0 += k1; x1 += k2 + 4u;
  G_A x0 += k2; x1 += k0 + 5u;
#undef G_A
#undef G_B
#undef RND
  o0 = x0; o1 = x1;
}

// Monotone map: u32 compare order == f32 value order.
__device__ inline uint32_t mono_f32(float v){
  const uint32_t bits = __float_as_uint(v);
  return (bits & 0x80000000u) ? ~bits : (bits | 0x80000000u);
}

// One DPP max step: combine with a lane-shifted copy (invalid srcs keep own value).
template<int CTRL>
__device__ __forceinline__ float dpp_max_step(float v){
  const int vi = __float_as_int(v);
  const int oi = __builtin_amdgcn_update_dpp(vi, vi, CTRL, 0xF, 0xF, false);
  return fmaxf(v, __int_as_float(oi));
}

// Full wave64 max, broadcast to all lanes via readlane(63).
__device__ __forceinline__ float wave_max_bcast(float v){
  v = dpp_max_step<0x111>(v);   // row_shr:1
  v = dpp_max_step<0x112>(v);   // row_shr:2
  v = dpp_max_step<0x114>(v);   // row_shr:4
  v = dpp_max_step<0x118>(v);   // row_shr:8  -> lane15 of each row = row max
  v = dpp_max_step<0x142>(v);   // row_bcast:15
  v = dpp_max_step<0x143>(v);   // row_bcast:31 -> lane63 = wave max
  return __int_as_float(__builtin_amdgcn_readlane(__float_as_int(v), 63));
}

__global__ __launch_bounds__(NT) void fused_sample_gather(
    const float* __restrict__ att, const float* __restrict__ wsi,
    float* __restrict__ out_attn, int2* __restrict__ ws_yx,
    f32x4* __restrict__ out4){
  const int tid  = threadIdx.x;
  const int wv   = tid >> 6;        // wave id 0..15
  const int lane = tid & 63;
  __shared__ unsigned long long ckey[NCAND];   // per-wave DESCENDING candidate lists
  __shared__ float             cprob[NCAND];
  __shared__ float redv[NW];
  __shared__ float ssum;

  // ================= phase 1: sampling (blocks 0..3) =================
  if (blockIdx.x < B){
    const int b = blockIdx.x;
    const float* a = att + b * GRID;

    // one float4 per thread: j = tid*4 + q (contiguous)
    const float4 va = reinterpret_cast<const float4*>(a)[tid];
    float areg[QP] = {va.x, va.y, va.z, va.w};

    // sum(attention row)
    float local = areg[0] + areg[1] + areg[2] + areg[3];
    #pragma unroll
    for (int d = 1; d < 64; d <<= 1) local += __shfl_xor(local, d, 64);
    if (lane == 0) redv[wv] = local;
    __syncthreads();
    if (tid == 0){
      float s = 0.f;
      #pragma unroll
      for (int w = 0; w < NW; ++w) s += redv[w];
      ssum = s;
    }
    __syncthreads();
    const float sum = ssum;

    // scores: log(prob + eps) + gumbel, all in registers
    float sreg[QP], preg[QP];
    #pragma unroll
    for (int q = 0; q < QP; ++q){
      const int j = (tid << 2) + q;
      const int e = b * GRID + j;                    // flat element in [0, 16384)
      uint32_t o0, o1;
      threefry2x32_k042(0u, (uint32_t)e, o0, o1);    // counter-mode: (hi, lo) = (0, e)
      const uint32_t bits = o0 ^ o1;                 // partitionable path XOR-folds
      const float u   = __uint_as_float((bits >> 9) | 0x3F800000u) - 1.0f;  // [0,1)
      const float gum = -logf(-logf(u + EPSF) + EPSF);
      const float prob = areg[q] / sum;
      preg[q] = prob;
      sreg[q] = logf(prob + EPSF) + gum;
    }

    float lm = fmaxf(fmaxf(sreg[0], sreg[1]), fmaxf(sreg[2], sreg[3]));

    // per-wave top-32 over its 256 elements, no barriers
    for (int k = 0; k < NP; ++k){
      const float bv = wave_max_bcast(lm);
      const unsigned long long mask = __ballot(lm == bv);
      const int wl = (int)(__ffsll(mask) - 1);       // lowest lane -> lowest j
      if (lane == wl){
        int qs = -1; float pa = 0.f;
        #pragma unroll
        for (int q = 0; q < QP; ++q){
          if (qs < 0 && sreg[q] == bv){ qs = q; pa = preg[q]; sreg[q] = -INFINITY; }
        }
        const int j = (tid << 2) + qs;
        ckey[wv * NP + k]  = ((unsigned long long)mono_f32(bv) << 32)
                           | (uint32_t)(GRID - 1 - j);
        cprob[wv * NP + k] = pa;
        lm = fmaxf(fmaxf(sreg[0], sreg[1]), fmaxf(sreg[2], sreg[3]));
      }
    }
    __syncthreads();

    // rank-merge: lists strictly descending, keys unique.
    if (tid < NCAND){
      const unsigned long long mykey = ckey[tid];
      const int myw = tid >> 5;
      int rank = tid & 31;               // position within own descending list
      for (int w = 0; w < NW; ++w){
        if (w == myw) continue;
        const unsigned long long* L = &ckey[w * NP];
        int c = 0;
        #pragma unroll
        for (int step = 16; step >= 1; step >>= 1){
          if (L[c + step - 1] > mykey) c += step;    // c stays <= 31
        }
        c += (L[c] > mykey) ? 1 : 0;                 // exact for count == 32
        rank += c;
      }
      if (rank < NP){
        const int j   = GRID - 1 - (int)(uint32_t)(mykey & 0xFFFFFFFFull);
        const int row = j >> 6, col = j & 63;
        int y0 = row * 32 - 48; y0 = y0 < 0 ? 0 : (y0 > 1920 ? 1920 : y0);
        int x0 = col * 32 - 48; x0 = x0 < 0 ? 0 : (x0 > 1920 ? 1920 : x0);
        ws_yx[b * NP + rank]    = make_int2(y0, x0);
        out_attn[b * NP + rank] = cprob[tid];
      }
    }
    __threadfence();   // make ws_yx visible device-wide before grid sync
  }

  cg::this_grid().sync();

  // ================= phase 2: gather (all blocks) =================
  int t = blockIdx.x * NT + tid;
  #pragma unroll
  for (int it = 0; it < GITER; ++it, t += NBLK * NT){
    const int l4   = t & 31;          // float4 within the 128-float row
    const int row  = t >> 5;          // [0, 4*32*3*128)
    const int r    = row & 127;
    const int tmp  = row >> 7;        // b*96 + n*3 + c
    const int c    = tmp % 3;
    const int bn   = tmp / 3;         // b*32 + n
    const int b    = bn >> 5;
    const int2 yx  = ws_yx[bn];       // (y0, x0); x0 multiple of 16 -> float4 aligned
    const size_t off = ((size_t)((b * 3 + c) * HW + yx.x + r)) * HW + (size_t)yx.y;
    const f32x4 v = *reinterpret_cast<const f32x4*>(wsi + off + (size_t)l4 * 4);
    __builtin_nontemporal_store(v, out4 + (size_t)row * 32 + l4);
  }
}
} // namespace

extern "C" void kernel_launch(void* const* d_in, const int* in_sizes, int n_in,
                              void* d_out, int out_size, void* d_ws, size_t ws_size,
                              hipStream_t stream) {
  const float* att = (const float*)d_in[2];
  const float* wsi = (const float*)d_in[3];
  float* out       = (float*)d_out;
  float* out_attn  = out + (size_t)B * NP * 3 * PATCH_ * PATCH_;  // 6,291,456
  int2*  ws_yx     = (int2*)d_ws;                                  // 4*32 pairs
  f32x4* out4      = (f32x4*)out;

  void* args[] = {(void*)&att, (void*)&wsi, (void*)&out_attn,
                  (void*)&ws_yx, (void*)&out4};
  hipLaunchCooperativeKernel((const void*)fused_sample_gather,
                             dim3(NBLK), dim3(NT), args, 0, stream);
}

// Round 9
// 51.602 us; speedup vs baseline: 1.1196x; 1.1196x over previous
//
#include <hip/hip_runtime.h>
#include <stdint.h>
#include <math.h>

// SamplePatches: gumbel top-k sampling (Threefry2x32 counter-mode, key 42) + patch gather.
// Inputs: d_in[0]=x_low (unused), d_in[1]=x_high (unused),
//         d_in[2]=attention [4,64,64] f32, d_in[3]=WSI [4,3,2048,2048] f32.
// Output: patches [4,32,3,128,128] f32 then sampled_attention [4,32] f32, concat flat.
//
// JAX defaults jax_threefry_partitionable=True: bits for element e are
// threefry2x32(key, (hi=0, lo=e)) with the two output words XOR-folded.
//
// SINGLE plain kernel, no grid sync: every block redundantly recomputes the
// (cheap, ~5us) sampling into block-local LDS, then gathers its patch slice.
// Per batch: 4 waves x 1024 elems each -> per-wave DPP top-32 (descending,
// unique keys), then rank = gallop-count over the batch's 4 lists.
// Total order = (value desc, j asc), identical to lax.top_k.

namespace {
constexpr int B      = 4;
constexpr int NP     = 32;     // N_PATCHES
constexpr int PATCH_ = 128;
constexpr int GRID   = 4096;   // 64*64 attention cells per batch
constexpr int HW     = 2048;
constexpr int NT     = 1024;   // threads per block
constexpr int NBLK   = 256;    // one block per CU; all co-resident, independent
constexpr int QP     = 16;     // scores per thread (4 batches x 4096 / 1024)
constexpr int TOT4   = B * NP * 3 * PATCH_ * PATCH_ / 4;   // 1,572,864 float4s
constexpr int GITER  = TOT4 / (NBLK * NT);                 // 6 per thread
constexpr float EPSF = 1e-12f;

typedef float f32x4 __attribute__((ext_vector_type(4)));

__device__ inline uint32_t rotl32(uint32_t x, uint32_t r){ return (x<<r)|(x>>(32u-r)); }

// Threefry-2x32 with key (0, 42)  == jax.random.key(42)
__device__ inline void threefry2x32_k042(uint32_t x0, uint32_t x1,
                                         uint32_t& o0, uint32_t& o1){
  const uint32_t k0 = 0u, k1 = 42u;
  const uint32_t k2 = k0 ^ k1 ^ 0x1BD11BDAu;
  x0 += k0; x1 += k1;
#define RND(r) { x0 += x1; x1 = rotl32(x1,(r)); x1 ^= x0; }
#define G_A RND(13) RND(15) RND(26) RND(6)
#define G_B RND(17) RND(29) RND(16) RND(24)
  G_A x0 += k1; x1 += k2 + 1u;
  G_B x0 += k2; x1 += k0 + 2u;
  G_A x0 += k0; x1 += k1 + 3u;
  G_B x0 += k1; x1 += k2 + 4u;
  G_A x0 += k2; x1 += k0 + 5u;
#undef G_A
#undef G_B
#undef RND
  o0 = x0; o1 = x1;
}

// Monotone map: u32 compare order == f32 value order.
__device__ inline uint32_t mono_f32(float v){
  const uint32_t bits = __float_as_uint(v);
  return (bits & 0x80000000u) ? ~bits : (bits | 0x80000000u);
}

// One DPP max step: combine with a lane-shifted copy (invalid srcs keep own value).
template<int CTRL>
__device__ __forceinline__ float dpp_max_step(float v){
  const int vi = __float_as_int(v);
  const int oi = __builtin_amdgcn_update_dpp(vi, vi, CTRL, 0xF, 0xF, false);
  return fmaxf(v, __int_as_float(oi));
}

// Full wave64 max, broadcast to all lanes via readlane(63).
__device__ __forceinline__ float wave_max_bcast(float v){
  v = dpp_max_step<0x111>(v);   // row_shr:1
  v = dpp_max_step<0x112>(v);   // row_shr:2
  v = dpp_max_step<0x114>(v);   // row_shr:4
  v = dpp_max_step<0x118>(v);   // row_shr:8  -> lane15 of each row = row max
  v = dpp_max_step<0x142>(v);   // row_bcast:15
  v = dpp_max_step<0x143>(v);   // row_bcast:31 -> lane63 = wave max
  return __int_as_float(__builtin_amdgcn_readlane(__float_as_int(v), 63));
}

__global__ __launch_bounds__(NT) void fused_sample_gather(
    const float* __restrict__ att, const float* __restrict__ wsi,
    float* __restrict__ out_attn, f32x4* __restrict__ out4){
  const int tid  = threadIdx.x;
  const int wv   = tid >> 6;        // wave id 0..15
  const int lane = tid & 63;
  const int b    = wv >> 2;         // batch this wave samples
  const int sw   = wv & 3;          // subwave within batch (0..3)
  __shared__ unsigned long long ckey[16 * NP];  // per-wave DESCENDING lists
  __shared__ float             cprob[16 * NP];
  __shared__ float redv[16];
  __shared__ int2  gtab[B * NP];    // bn -> (y0, x0), block-local

  // ---- load 16 contiguous floats: j = sw*1024 + lane*16 + q ----
  const int jb = (sw << 10) + (lane << 4);
  const float4* a4 = reinterpret_cast<const float4*>(att + b * GRID + jb);
  const float4 v0 = a4[0], v1 = a4[1], v2 = a4[2], v3 = a4[3];
  float areg[QP] = {v0.x,v0.y,v0.z,v0.w, v1.x,v1.y,v1.z,v1.w,
                    v2.x,v2.y,v2.z,v2.w, v3.x,v3.y,v3.z,v3.w};

  // ---- per-batch sum: 4 wave partials, then 4 broadcast LDS reads ----
  float local = 0.f;
  #pragma unroll
  for (int q = 0; q < QP; ++q) local += areg[q];
  #pragma unroll
  for (int d = 1; d < 64; d <<= 1) local += __shfl_xor(local, d, 64);
  if (lane == 0) redv[wv] = local;
  __syncthreads();
  const float sum = redv[b*4] + redv[b*4+1] + redv[b*4+2] + redv[b*4+3];

  // ---- scores: log(prob + eps) + gumbel, all in registers ----
  float sreg[QP];
  #pragma unroll
  for (int q = 0; q < QP; ++q){
    const int j = jb + q;
    const int e = b * GRID + j;                    // flat element in [0, 16384)
    uint32_t o0, o1;
    threefry2x32_k042(0u, (uint32_t)e, o0, o1);    // counter-mode: (hi, lo) = (0, e)
    const uint32_t bits = o0 ^ o1;                 // partitionable path XOR-folds
    const float u   = __uint_as_float((bits >> 9) | 0x3F800000u) - 1.0f;  // [0,1)
    const float gum = -logf(-logf(u + EPSF) + EPSF);
    sreg[q] = logf(areg[q] / sum + EPSF) + gum;
  }

  float lm = -INFINITY;
  #pragma unroll
  for (int q = 0; q < QP; ++q) lm = fmaxf(lm, sreg[q]);

  // ---- per-wave top-32 over its 1024 elements, no barriers ----
  for (int k = 0; k < NP; ++k){
    const float bv = wave_max_bcast(lm);
    const unsigned long long mask = __ballot(lm == bv);
    const int wl = (int)(__ffsll(mask) - 1);       // lowest lane -> lowest j
    if (lane == wl){
      int qs = -1; float pa = 0.f;
      #pragma unroll
      for (int q = 0; q < QP; ++q){
        if (qs < 0 && sreg[q] == bv){ qs = q; pa = areg[q]; sreg[q] = -INFINITY; }
      }
      const int j = jb + qs;
      ckey[wv * NP + k]  = ((unsigned long long)mono_f32(bv) << 32)
                         | (uint32_t)(GRID - 1 - j);
      cprob[wv * NP + k] = pa / sum;
      lm = -INFINITY;
      #pragma unroll
      for (int q = 0; q < QP; ++q) lm = fmaxf(lm, sreg[q]);
    }
  }
  __syncthreads();

  // ---- rank-merge per batch: count over the batch's 4 descending lists
  //      (own list included: count there == own position). rank < 32 -> emit.
  if (tid < 16 * NP){                // 512 candidates, 128 per batch
    const unsigned long long mykey = ckey[tid];
    const int b2 = tid >> 7;         // candidate's batch
    int rank = 0;
    #pragma unroll
    for (int w = 0; w < 4; ++w){
      const unsigned long long* L = &ckey[(b2 * 4 + w) * NP];
      int c = 0;
      #pragma unroll
      for (int step = 16; step >= 1; step >>= 1){
        if (L[c + step - 1] > mykey) c += step;    // c stays <= 31
      }
      c += (L[c] > mykey) ? 1 : 0;                 // exact for count == 32
      rank += c;
    }
    if (rank < NP){
      const int j   = GRID - 1 - (int)(uint32_t)(mykey & 0xFFFFFFFFull);
      const int row = j >> 6, col = j & 63;
      int y0 = row * 32 - 48; y0 = y0 < 0 ? 0 : (y0 > 1920 ? 1920 : y0);
      int x0 = col * 32 - 48; x0 = x0 < 0 ? 0 : (x0 > 1920 ? 1920 : x0);
      gtab[b2 * NP + rank] = make_int2(y0, x0);
      if (blockIdx.x == 0) out_attn[b2 * NP + rank] = cprob[tid];
    }
  }
  __syncthreads();

  // ---- gather phase: 6 float4s per thread, indices from block-local LDS ----
  int t = blockIdx.x * NT + tid;
  #pragma unroll
  for (int it = 0; it < GITER; ++it, t += NBLK * NT){
    const int l4   = t & 31;          // float4 within the 128-float row
    const int row  = t >> 5;          // [0, 4*32*3*128)
    const int r    = row & 127;
    const int tmp  = row >> 7;        // b*96 + n*3 + c
    const int c    = tmp % 3;
    const int bn   = tmp / 3;         // b*32 + n
    const int bb   = bn >> 5;
    const int2 yx  = gtab[bn];        // (y0, x0); x0 multiple of 16 -> aligned
    const size_t off = ((size_t)((bb * 3 + c) * HW + yx.x + r)) * HW + (size_t)yx.y;
    const f32x4 v = *reinterpret_cast<const f32x4*>(wsi + off + (size_t)l4 * 4);
    __builtin_nontemporal_store(v, out4 + (size_t)row * 32 + l4);
  }
}
} // namespace

extern "C" void kernel_launch(void* const* d_in, const int* in_sizes, int n_in,
                              void* d_out, int out_size, void* d_ws, size_t ws_size,
                              hipStream_t stream) {
  const float* att = (const float*)d_in[2];
  const float* wsi = (const float*)d_in[3];
  float* out       = (float*)d_out;
  float* out_attn  = out + (size_t)B * NP * 3 * PATCH_ * PATCH_;  // 6,291,456

  fused_sample_gather<<<NBLK, NT, 0, stream>>>(att, wsi, out_attn, (f32x4*)out);
}

// Round 10
// 30.809 us; speedup vs baseline: 1.8752x; 1.6749x over previous
//
#include <hip/hip_runtime.h>
#include <stdint.h>
#include <math.h>

// SamplePatches: gumbel top-k sampling (Threefry2x32 counter-mode, key 42) + patch gather.
// Inputs: d_in[0]=x_low (unused), d_in[1]=x_high (unused),
//         d_in[2]=attention [4,64,64] f32, d_in[3]=WSI [4,3,2048,2048] f32.
// Output: patches [4,32,3,128,128] f32 then sampled_attention [4,32] f32, concat flat.
//
// JAX defaults jax_threefry_partitionable=True: bits for element e are
// threefry2x32(key, (hi=0, lo=e)) with the two output words XOR-folded.
//
// SINGLE plain kernel, no grid sync, BATCH-SPECIALIZED redundancy: each of 256
// blocks samples ONLY its own batch (64 blocks/batch recompute the same cheap
// top-32 into block-local LDS; identical math to the verified 2-kernel version),
// then gathers its 1/64 slice of that batch's patches.
// Selection: 16 waves, per-wave DPP top-32 (descending, unique keys), gallop
// rank-merge. Total order = (value desc, j asc), identical to lax.top_k.

namespace {
constexpr int B      = 4;
constexpr int NP     = 32;     // N_PATCHES
constexpr int PATCH_ = 128;
constexpr int GRID   = 4096;   // 64*64 attention cells per batch
constexpr int HW     = 2048;
constexpr int NT     = 1024;   // threads per block
constexpr int BPB    = 64;     // blocks per batch
constexpr int NBLK   = B * BPB;          // 256 blocks, one per CU
constexpr int NW     = NT / 64;          // 16 waves
constexpr int QP     = GRID / NT;        // 4 scores per thread
constexpr int NCAND  = NW * NP;          // 512 merge candidates
// per-batch gather: 32*3*128 rows x 32 float4 = 393,216 f4 = 64 blk x 1024 thr x 6
constexpr int GITER  = 6;
constexpr float EPSF = 1e-12f;

typedef float f32x4 __attribute__((ext_vector_type(4)));

__device__ inline uint32_t rotl32(uint32_t x, uint32_t r){ return (x<<r)|(x>>(32u-r)); }

// Threefry-2x32 with key (0, 42)  == jax.random.key(42)
__device__ inline void threefry2x32_k042(uint32_t x0, uint32_t x1,
                                         uint32_t& o0, uint32_t& o1){
  const uint32_t k0 = 0u, k1 = 42u;
  const uint32_t k2 = k0 ^ k1 ^ 0x1BD11BDAu;
  x0 += k0; x1 += k1;
#define RND(r) { x0 += x1; x1 = rotl32(x1,(r)); x1 ^= x0; }
#define G_A RND(13) RND(15) RND(26) RND(6)
#define G_B RND(17) RND(29) RND(16) RND(24)
  G_A x0 += k1; x1 += k2 + 1u;
  G_B x0 += k2; x1 += k0 + 2u;
  G_A x0 += k0; x1 += k1 + 3u;
  G_B x0 += k1; x1 += k2 + 4u;
  G_A x0 += k2; x1 += k0 + 5u;
#undef G_A
#undef G_B
#undef RND
  o0 = x0; o1 = x1;
}

// Monotone map: u32 compare order == f32 value order.
__device__ inline uint32_t mono_f32(float v){
  const uint32_t bits = __float_as_uint(v);
  return (bits & 0x80000000u) ? ~bits : (bits | 0x80000000u);
}

// One DPP max step: combine with a lane-shifted copy (invalid srcs keep own value).
template<int CTRL>
__device__ __forceinline__ float dpp_max_step(float v){
  const int vi = __float_as_int(v);
  const int oi = __builtin_amdgcn_update_dpp(vi, vi, CTRL, 0xF, 0xF, false);
  return fmaxf(v, __int_as_float(oi));
}

// Full wave64 max, broadcast to all lanes via readlane(63).
__device__ __forceinline__ float wave_max_bcast(float v){
  v = dpp_max_step<0x111>(v);   // row_shr:1
  v = dpp_max_step<0x112>(v);   // row_shr:2
  v = dpp_max_step<0x114>(v);   // row_shr:4
  v = dpp_max_step<0x118>(v);   // row_shr:8  -> lane15 of each row = row max
  v = dpp_max_step<0x142>(v);   // row_bcast:15
  v = dpp_max_step<0x143>(v);   // row_bcast:31 -> lane63 = wave max
  return __int_as_float(__builtin_amdgcn_readlane(__float_as_int(v), 63));
}

__global__ __launch_bounds__(NT) void fused_sample_gather(
    const float* __restrict__ att, const float* __restrict__ wsi,
    float* __restrict__ out_attn, f32x4* __restrict__ out4){
  const int tid  = threadIdx.x;
  const int wv   = tid >> 6;        // wave id 0..15
  const int lane = tid & 63;
  const int b    = blockIdx.x >> 6; // this block's batch
  const int g    = blockIdx.x & 63; // slice index within batch
  __shared__ unsigned long long ckey[NCAND];   // per-wave DESCENDING lists
  __shared__ float             cprob[NCAND];
  __shared__ float redv[NW];
  __shared__ float ssum;
  __shared__ int2  gtab[NP];        // n -> (y0, x0), this batch only

  // ================= sampling (this batch only; identical to verified 2-kernel) =====
  const float* a = att + b * GRID;

  // one float4 per thread: j = tid*4 + q (contiguous)
  const float4 va = reinterpret_cast<const float4*>(a)[tid];
  float areg[QP] = {va.x, va.y, va.z, va.w};

  // sum(attention row)
  float local = areg[0] + areg[1] + areg[2] + areg[3];
  #pragma unroll
  for (int d = 1; d < 64; d <<= 1) local += __shfl_xor(local, d, 64);
  if (lane == 0) redv[wv] = local;
  __syncthreads();
  if (tid == 0){
    float s = 0.f;
    #pragma unroll
    for (int w = 0; w < NW; ++w) s += redv[w];
    ssum = s;
  }
  __syncthreads();
  const float sum = ssum;

  // scores: log(prob + eps) + gumbel, all in registers
  float sreg[QP], preg[QP];
  #pragma unroll
  for (int q = 0; q < QP; ++q){
    const int j = (tid << 2) + q;
    const int e = b * GRID + j;                    // flat element in [0, 16384)
    uint32_t o0, o1;
    threefry2x32_k042(0u, (uint32_t)e, o0, o1);    // counter-mode: (hi, lo) = (0, e)
    const uint32_t bits = o0 ^ o1;                 // partitionable path XOR-folds
    const float u   = __uint_as_float((bits >> 9) | 0x3F800000u) - 1.0f;  // [0,1)
    const float gum = -logf(-logf(u + EPSF) + EPSF);
    const float prob = areg[q] / sum;
    preg[q] = prob;
    sreg[q] = logf(prob + EPSF) + gum;
  }

  float lm = fmaxf(fmaxf(sreg[0], sreg[1]), fmaxf(sreg[2], sreg[3]));

  // per-wave top-32 over its 256 elements, no barriers
  for (int k = 0; k < NP; ++k){
    const float bv = wave_max_bcast(lm);
    const unsigned long long mask = __ballot(lm == bv);
    const int wl = (int)(__ffsll(mask) - 1);       // lowest lane -> lowest j
    if (lane == wl){
      int qs = -1; float pa = 0.f;
      #pragma unroll
      for (int q = 0; q < QP; ++q){
        if (qs < 0 && sreg[q] == bv){ qs = q; pa = preg[q]; sreg[q] = -INFINITY; }
      }
      const int j = (tid << 2) + qs;
      ckey[wv * NP + k]  = ((unsigned long long)mono_f32(bv) << 32)
                         | (uint32_t)(GRID - 1 - j);
      cprob[wv * NP + k] = pa;
      lm = fmaxf(fmaxf(sreg[0], sreg[1]), fmaxf(sreg[2], sreg[3]));
    }
  }
  __syncthreads();

  // rank-merge: 16 strictly-descending lists, keys unique; 5-probe gallop each.
  if (tid < NCAND){
    const unsigned long long mykey = ckey[tid];
    const int myw = tid >> 5;
    int rank = tid & 31;               // position within own descending list
    for (int w = 0; w < NW; ++w){
      if (w == myw) continue;
      const unsigned long long* L = &ckey[w * NP];
      int c = 0;
      #pragma unroll
      for (int step = 16; step >= 1; step >>= 1){
        if (L[c + step - 1] > mykey) c += step;    // c stays <= 31
      }
      c += (L[c] > mykey) ? 1 : 0;                 // exact for count == 32
      rank += c;
    }
    if (rank < NP){
      const int j   = GRID - 1 - (int)(uint32_t)(mykey & 0xFFFFFFFFull);
      const int row = j >> 6, col = j & 63;
      int y0 = row * 32 - 48; y0 = y0 < 0 ? 0 : (y0 > 1920 ? 1920 : y0);
      int x0 = col * 32 - 48; x0 = x0 < 0 ? 0 : (x0 > 1920 ? 1920 : x0);
      gtab[rank] = make_int2(y0, x0);
      if (g == 0) out_attn[b * NP + rank] = cprob[tid];
    }
  }
  __syncthreads();

  // ================= gather: this block's 1/64 slice of its batch ============
  // per batch: rows = 32*3*128 = 12288, each row = 32 float4.
  int t = g * NT + tid;                       // [0, 65536) per iteration step
  #pragma unroll
  for (int it = 0; it < GITER; ++it, t += BPB * NT){
    const int l4   = t & 31;          // float4 within the 128-float row
    const int rowb = t >> 5;          // [0, 12288) within batch
    const int r    = rowb & 127;
    const int tmp  = rowb >> 7;       // n*3 + c, [0, 96)
    const int c    = tmp % 3;
    const int n    = tmp / 3;
    const int2 yx  = gtab[n];         // (y0, x0); x0 multiple of 16 -> aligned
    const size_t off = ((size_t)((b * 3 + c) * HW + yx.x + r)) * HW + (size_t)yx.y;
    const f32x4 v = *reinterpret_cast<const f32x4*>(wsi + off + (size_t)l4 * 4);
    __builtin_nontemporal_store(v, out4 + ((size_t)b * 12288 + rowb) * 32 + l4);
  }
}
} // namespace

extern "C" void kernel_launch(void* const* d_in, const int* in_sizes, int n_in,
                              void* d_out, int out_size, void* d_ws, size_t ws_size,
                              hipStream_t stream) {
  const float* att = (const float*)d_in[2];
  const float* wsi = (const float*)d_in[3];
  float* out       = (float*)d_out;
  float* out_attn  = out + (size_t)B * NP * 3 * PATCH_ * PATCH_;  // 6,291,456

  fused_sample_gather<<<NBLK, NT, 0, stream>>>(att, wsi, out_attn, (f32x4*)out);
}

// Round 11
// 25.153 us; speedup vs baseline: 2.2969x; 1.2249x over previous
//
#include <hip/hip_runtime.h>
#include <stdint.h>
#include <math.h>

// SamplePatches: gumbel top-k sampling (Threefry2x32 counter-mode, key 42) + patch gather.
// Inputs: d_in[0]=x_low (unused), d_in[1]=x_high (unused),
//         d_in[2]=attention [4,64,64] f32, d_in[3]=WSI [4,3,2048,2048] f32.
// Output: patches [4,32,3,128,128] f32 then sampled_attention [4,32] f32, concat flat.
//
// JAX defaults jax_threefry_partitionable=True: bits for element e are
// threefry2x32(key, (hi=0, lo=e)) with the two output words XOR-folded.
//
// SINGLE plain kernel, batch-specialized redundancy (64 blocks/batch recompute
// the same selection into block-local LDS). Selection accelerated by an EXACT
// threshold early-exit:
//   stage A: each of 16 waves extracts its local top-8 (DPP max passes).
//   thr = 32nd-largest of the 128 stage-A keys. True batch-32nd >= thr, so a
//   wave may stop once all its remaining elements are < thr (upper-bound key
//   compare, wave-uniform). Candidate lists are zero-padded; gallop rank-merge
//   emits rank < 32. Total order = (value desc, j asc), identical to lax.top_k.

namespace {
constexpr int B      = 4;
constexpr int NP     = 32;     // N_PATCHES
constexpr int PATCH_ = 128;
constexpr int GRID   = 4096;   // 64*64 attention cells per batch
constexpr int HW     = 2048;
constexpr int NT     = 1024;   // threads per block
constexpr int BPB    = 64;     // blocks per batch
constexpr int NBLK   = B * BPB;          // 256 blocks, one per CU
constexpr int NW     = NT / 64;          // 16 waves
constexpr int QP     = GRID / NT;        // 4 scores per thread
constexpr int NCAND  = NW * NP;          // 512 candidate slots (zero-padded)
constexpr int KA     = 8;                // stage-A extractions per wave
constexpr int GITER  = 6;                // gather float4s per thread
constexpr float EPSF = 1e-12f;

typedef float f32x4 __attribute__((ext_vector_type(4)));

__device__ inline uint32_t rotl32(uint32_t x, uint32_t r){ return (x<<r)|(x>>(32u-r)); }

// Threefry-2x32 with key (0, 42)  == jax.random.key(42)
__device__ inline void threefry2x32_k042(uint32_t x0, uint32_t x1,
                                         uint32_t& o0, uint32_t& o1){
  const uint32_t k0 = 0u, k1 = 42u;
  const uint32_t k2 = k0 ^ k1 ^ 0x1BD11BDAu;
  x0 += k0; x1 += k1;
#define RND(r) { x0 += x1; x1 = rotl32(x1,(r)); x1 ^= x0; }
#define G_A RND(13) RND(15) RND(26) RND(6)
#define G_B RND(17) RND(29) RND(16) RND(24)
  G_A x0 += k1; x1 += k2 + 1u;
  G_B x0 += k2; x1 += k0 + 2u;
  G_A x0 += k0; x1 += k1 + 3u;
  G_B x0 += k1; x1 += k2 + 4u;
  G_A x0 += k2; x1 += k0 + 5u;
#undef G_A
#undef G_B
#undef RND
  o0 = x0; o1 = x1;
}

// Monotone map: u32 compare order == f32 value order. Always > 0 for finite v.
__device__ inline uint32_t mono_f32(float v){
  const uint32_t bits = __float_as_uint(v);
  return (bits & 0x80000000u) ? ~bits : (bits | 0x80000000u);
}

// One DPP max step: combine with a lane-shifted copy (invalid srcs keep own value).
template<int CTRL>
__device__ __forceinline__ float dpp_max_step(float v){
  const int vi = __float_as_int(v);
  const int oi = __builtin_amdgcn_update_dpp(vi, vi, CTRL, 0xF, 0xF, false);
  return fmaxf(v, __int_as_float(oi));
}

// Full wave64 max, broadcast to all lanes via readlane(63).
__device__ __forceinline__ float wave_max_bcast(float v){
  v = dpp_max_step<0x111>(v);   // row_shr:1
  v = dpp_max_step<0x112>(v);   // row_shr:2
  v = dpp_max_step<0x114>(v);   // row_shr:4
  v = dpp_max_step<0x118>(v);   // row_shr:8  -> lane15 of each row = row max
  v = dpp_max_step<0x142>(v);   // row_bcast:15
  v = dpp_max_step<0x143>(v);   // row_bcast:31 -> lane63 = wave max
  return __int_as_float(__builtin_amdgcn_readlane(__float_as_int(v), 63));
}

__global__ __launch_bounds__(NT) void fused_sample_gather(
    const float* __restrict__ att, const float* __restrict__ wsi,
    float* __restrict__ out_attn, f32x4* __restrict__ out4){
  const int tid  = threadIdx.x;
  const int wv   = tid >> 6;        // wave id 0..15
  const int lane = tid & 63;
  const int b    = blockIdx.x >> 6; // this block's batch
  const int g    = blockIdx.x & 63; // slice index within batch
  __shared__ unsigned long long ckey[NCAND];   // per-wave DESCENDING lists, 0-padded
  __shared__ float             cprob[NCAND];
  __shared__ float redv[NW];
  __shared__ float ssum;
  __shared__ unsigned long long sthr;
  __shared__ int2  gtab[NP];        // n -> (y0, x0), this batch only

  // ================= sampling (this batch only) =================
  const float* a = att + b * GRID;

  // one float4 per thread: j = tid*4 + q (contiguous)
  const float4 va = reinterpret_cast<const float4*>(a)[tid];
  float areg[QP] = {va.x, va.y, va.z, va.w};

  // zero-pad candidate lists (covered by the sum barrier below)
  if (tid < NCAND) ckey[tid] = 0ull;

  // sum(attention row)
  float local = areg[0] + areg[1] + areg[2] + areg[3];
  #pragma unroll
  for (int d = 1; d < 64; d <<= 1) local += __shfl_xor(local, d, 64);
  if (lane == 0) redv[wv] = local;
  __syncthreads();
  if (tid == 0){
    float s = 0.f;
    #pragma unroll
    for (int w = 0; w < NW; ++w) s += redv[w];
    ssum = s;
  }
  __syncthreads();
  const float sum = ssum;

  // scores: log(prob + eps) + gumbel, all in registers (exact ocml math,
  // bit-identical to the verified rounds)
  float sreg[QP], preg[QP];
  #pragma unroll
  for (int q = 0; q < QP; ++q){
    const int j = (tid << 2) + q;
    const int e = b * GRID + j;                    // flat element in [0, 16384)
    uint32_t o0, o1;
    threefry2x32_k042(0u, (uint32_t)e, o0, o1);    // counter-mode: (hi, lo) = (0, e)
    const uint32_t bits = o0 ^ o1;                 // partitionable path XOR-folds
    const float u   = __uint_as_float((bits >> 9) | 0x3F800000u) - 1.0f;  // [0,1)
    const float gum = -logf(-logf(u + EPSF) + EPSF);
    const float prob = areg[q] / sum;
    preg[q] = prob;
    sreg[q] = logf(prob + EPSF) + gum;
  }

  float lm = fmaxf(fmaxf(sreg[0], sreg[1]), fmaxf(sreg[2], sreg[3]));

  // ---- stage A: per-wave top-8 (descending, unique keys), no barriers ----
  #pragma unroll 1
  for (int k = 0; k < KA; ++k){
    const float bv = wave_max_bcast(lm);
    const unsigned long long mask = __ballot(lm == bv);
    const int wl = (int)(__ffsll(mask) - 1);       // lowest lane -> lowest j
    if (lane == wl){
      int qs = -1; float pa = 0.f;
      #pragma unroll
      for (int q = 0; q < QP; ++q){
        if (qs < 0 && sreg[q] == bv){ qs = q; pa = preg[q]; sreg[q] = -INFINITY; }
      }
      const int j = (tid << 2) + qs;
      ckey[wv * NP + k]  = ((unsigned long long)mono_f32(bv) << 32)
                         | (uint32_t)(GRID - 1 - j);
      cprob[wv * NP + k] = pa;
      lm = fmaxf(fmaxf(sreg[0], sreg[1]), fmaxf(sreg[2], sreg[3]));
    }
  }
  __syncthreads();

  // ---- thr = 32nd-largest of the 128 stage-A keys (exact; keys unique) ----
  if (tid < NW * KA){
    const unsigned long long mykey = ckey[(tid >> 3) * NP + (tid & 7)];
    int rank = 0;
    #pragma unroll 8
    for (int c = 0; c < NW * KA; ++c)
      rank += (ckey[(c >> 3) * NP + (c & 7)] > mykey) ? 1 : 0;
    if (rank == NP - 1) sthr = mykey;
  }
  __syncthreads();
  const unsigned long long thr = sthr;

  // ---- stage B: continue only while this wave can still beat thr ----
  // Upper-bound key (low field 0xFFFFFFFF) is unattainable by real keys, so
  // ub <= thr  =>  all remaining elements strictly below thr <= true-32nd.
  #pragma unroll 1
  for (int k = KA; k < NP; ++k){
    const float bv = wave_max_bcast(lm);
    const unsigned long long ub =
        ((unsigned long long)mono_f32(bv) << 32) | 0xFFFFFFFFull;
    if (ub <= thr) break;                          // wave-uniform exit
    const unsigned long long mask = __ballot(lm == bv);
    const int wl = (int)(__ffsll(mask) - 1);
    if (lane == wl){
      int qs = -1; float pa = 0.f;
      #pragma unroll
      for (int q = 0; q < QP; ++q){
        if (qs < 0 && sreg[q] == bv){ qs = q; pa = preg[q]; sreg[q] = -INFINITY; }
      }
      const int j = (tid << 2) + qs;
      ckey[wv * NP + k]  = ((unsigned long long)mono_f32(bv) << 32)
                         | (uint32_t)(GRID - 1 - j);
      cprob[wv * NP + k] = pa;
      lm = fmaxf(fmaxf(sreg[0], sreg[1]), fmaxf(sreg[2], sreg[3]));
    }
  }
  __syncthreads();

  // ---- rank-merge: 16 nonincreasing zero-padded lists; 5-probe gallop each.
  //      Real keys > 0; zero-pad never counts; zero-key threads rank >= 128.
  if (tid < NCAND){
    const unsigned long long mykey = ckey[tid];
    const int myw = tid >> 5;
    int rank = tid & 31;               // position within own descending list
    for (int w = 0; w < NW; ++w){
      if (w == myw) continue;
      const unsigned long long* L = &ckey[w * NP];
      int c = 0;
      #pragma unroll
      for (int step = 16; step >= 1; step >>= 1){
        if (L[c + step - 1] > mykey) c += step;    // c stays <= 31
      }
      c += (L[c] > mykey) ? 1 : 0;                 // exact for count == 32
      rank += c;
    }
    if (rank < NP && mykey != 0ull){
      const int j   = GRID - 1 - (int)(uint32_t)(mykey & 0xFFFFFFFFull);
      const int row = j >> 6, col = j & 63;
      int y0 = row * 32 - 48; y0 = y0 < 0 ? 0 : (y0 > 1920 ? 1920 : y0);
      int x0 = col * 32 - 48; x0 = x0 < 0 ? 0 : (x0 > 1920 ? 1920 : x0);
      gtab[rank] = make_int2(y0, x0);
      if (g == 0) out_attn[b * NP + rank] = cprob[tid];
    }
  }
  __syncthreads();

  // ================= gather: this block's 1/64 slice of its batch ============
  // per batch: rows = 32*3*128 = 12288, each row = 32 float4.
  int t = g * NT + tid;                       // [0, 65536) per iteration step
  #pragma unroll
  for (int it = 0; it < GITER; ++it, t += BPB * NT){
    const int l4   = t & 31;          // float4 within the 128-float row
    const int rowb = t >> 5;          // [0, 12288) within batch
    const int r    = rowb & 127;
    const int tmp  = rowb >> 7;       // n*3 + c, [0, 96)
    const int c    = tmp % 3;
    const int n    = tmp / 3;
    const int2 yx  = gtab[n];         // (y0, x0); x0 multiple of 16 -> aligned
    const size_t off = ((size_t)((b * 3 + c) * HW + yx.x + r)) * HW + (size_t)yx.y;
    const f32x4 v = *reinterpret_cast<const f32x4*>(wsi + off + (size_t)l4 * 4);
    __builtin_nontemporal_store(v, out4 + ((size_t)b * 12288 + rowb) * 32 + l4);
  }
}
} // namespace

extern "C" void kernel_launch(void* const* d_in, const int* in_sizes, int n_in,
                              void* d_out, int out_size, void* d_ws, size_t ws_size,
                              hipStream_t stream) {
  const float* att = (const float*)d_in[2];
  const float* wsi = (const float*)d_in[3];
  float* out       = (float*)d_out;
  float* out_attn  = out + (size_t)B * NP * 3 * PATCH_ * PATCH_;  // 6,291,456

  fused_sample_gather<<<NBLK, NT, 0, stream>>>(att, wsi, out_attn, (f32x4*)out);
}

// Round 12
// 19.663 us; speedup vs baseline: 2.9383x; 1.2792x over previous
//
#include <hip/hip_runtime.h>
#include <stdint.h>
#include <math.h>

// SamplePatches: gumbel top-k sampling (Threefry2x32 counter-mode, key 42) + patch gather.
// Inputs: d_in[0]=x_low (unused), d_in[1]=x_high (unused),
//         d_in[2]=attention [4,64,64] f32, d_in[3]=WSI [4,3,2048,2048] f32.
// Output: patches [4,32,3,128,128] f32 then sampled_attention [4,32] f32, concat flat.
//
// JAX defaults jax_threefry_partitionable=True: bits for element e are
// threefry2x32(key, (hi=0, lo=e)) with the two output words XOR-folded.
//
// SINGLE plain kernel, batch-specialized redundancy (64 blocks/batch).
// Selection via EXACT histogram select:
//   - fast __logf scores -> monotone u32 keys -> 8192-bin LDS histogram
//   - one-wave suffix scan finds bin t* of the 32nd-largest fast key
//   - candidates = all elements in bins >= t*-2 (margin >> fast-vs-exact error,
//     so candidates provably contain the exact top-32)
//   - candidates re-scored with the EXACT ocml logf formula (bit-identical to
//     all prior passing rounds), ranked by (value desc, j asc) == lax.top_k.

namespace {
constexpr int B      = 4;
constexpr int NP     = 32;     // N_PATCHES
constexpr int PATCH_ = 128;
constexpr int GRID   = 4096;   // 64*64 attention cells per batch
constexpr int HW     = 2048;
constexpr int NT     = 1024;   // threads per block
constexpr int BPB    = 64;     // blocks per batch
constexpr int NBLK   = B * BPB;          // 256 blocks, one per CU
constexpr int NW     = NT / 64;          // 16 waves
constexpr int QP     = GRID / NT;        // 4 scores per thread
constexpr int NBIN   = 8192;   // fine bins: mono >> 19 (order-preserving)
constexpr int NCB    = 128;    // coarse bins: 64 fine each
constexpr int MAXC   = 512;    // candidate capacity (expected ~60-90)
constexpr int GITER  = 6;      // gather float4s per thread
constexpr float EPSF = 1e-12f;

typedef float f32x4 __attribute__((ext_vector_type(4)));

__device__ inline uint32_t rotl32(uint32_t x, uint32_t r){ return (x<<r)|(x>>(32u-r)); }

// Threefry-2x32 with key (0, 42)  == jax.random.key(42)
__device__ inline void threefry2x32_k042(uint32_t x0, uint32_t x1,
                                         uint32_t& o0, uint32_t& o1){
  const uint32_t k0 = 0u, k1 = 42u;
  const uint32_t k2 = k0 ^ k1 ^ 0x1BD11BDAu;
  x0 += k0; x1 += k1;
#define RND(r) { x0 += x1; x1 = rotl32(x1,(r)); x1 ^= x0; }
#define G_A RND(13) RND(15) RND(26) RND(6)
#define G_B RND(17) RND(29) RND(16) RND(24)
  G_A x0 += k1; x1 += k2 + 1u;
  G_B x0 += k2; x1 += k0 + 2u;
  G_A x0 += k0; x1 += k1 + 3u;
  G_B x0 += k1; x1 += k2 + 4u;
  G_A x0 += k2; x1 += k0 + 5u;
#undef G_A
#undef G_B
#undef RND
  o0 = x0; o1 = x1;
}

// Monotone map: u32 compare order == f32 value order.
__device__ inline uint32_t mono_f32(float v){
  const uint32_t bits = __float_as_uint(v);
  return (bits & 0x80000000u) ? ~bits : (bits | 0x80000000u);
}

// uniform bits -> [0,1) float, identical to jax (bits>>9 | one) - 1
__device__ inline float u01(uint32_t bits){
  return __uint_as_float((bits >> 9) | 0x3F800000u) - 1.0f;
}

__global__ __launch_bounds__(NT) void fused_sample_gather(
    const float* __restrict__ att, const float* __restrict__ wsi,
    float* __restrict__ out_attn, f32x4* __restrict__ out4){
  const int tid  = threadIdx.x;
  const int wv   = tid >> 6;        // wave id 0..15
  const int lane = tid & 63;
  const int b    = blockIdx.x >> 6; // this block's batch
  const int g    = blockIdx.x & 63; // slice index within batch
  __shared__ uint32_t hist[NBIN];   // 32 KB
  __shared__ uint32_t coarse[NCB];
  __shared__ float redv[NW];
  __shared__ float ssum;
  __shared__ int   scnt;
  __shared__ int   stcut;
  __shared__ unsigned short candj[MAXC];
  __shared__ unsigned long long dkey[MAXC];
  __shared__ float dprob[MAXC];
  __shared__ int2  gtab[NP];        // n -> (y0, x0), this batch only

  const float* a = att + b * GRID;

  // one float4 per thread: j = tid*4 + q (contiguous)
  const float4 va = reinterpret_cast<const float4*>(a)[tid];
  float areg[QP] = {va.x, va.y, va.z, va.w};

  // zero histogram + counters (covered by the sum barrier below)
  #pragma unroll
  for (int i = 0; i < NBIN / NT; ++i) hist[i * NT + tid] = 0u;
  if (tid == 0) scnt = 0;

  // ---- sum(attention row): UNCHANGED bit-exact path ----
  float local = areg[0] + areg[1] + areg[2] + areg[3];
  #pragma unroll
  for (int d = 1; d < 64; d <<= 1) local += __shfl_xor(local, d, 64);
  if (lane == 0) redv[wv] = local;
  __syncthreads();
  if (tid == 0){
    float s = 0.f;
    #pragma unroll
    for (int w = 0; w < NW; ++w) s += redv[w];
    ssum = s;
  }
  __syncthreads();
  const float sum = ssum;

  // ---- fast scores (filter only) -> monotone keys -> histogram ----
  uint32_t kreg[QP];
  #pragma unroll
  for (int q = 0; q < QP; ++q){
    const int e = b * GRID + (tid << 2) + q;       // flat element in [0, 16384)
    uint32_t o0, o1;
    threefry2x32_k042(0u, (uint32_t)e, o0, o1);
    const float u = u01(o0 ^ o1);
    const float gum = -__logf(-__logf(u + EPSF) + EPSF);   // fast v_log path
    const float s   = __logf(areg[q] / sum + EPSF) + gum;
    kreg[q] = mono_f32(s);
    atomicAdd(&hist[kreg[q] >> 19], 1u);
  }
  __syncthreads();

  // ---- coarse histogram: 128 bins of 64 fine each ----
  if (tid < NCB){
    uint32_t s = 0;
    #pragma unroll
    for (int i = 0; i < 64; ++i) s += hist[tid * 64 + i];
    coarse[tid] = s;
  }
  __syncthreads();

  // ---- one-wave suffix scan: find bin t* of the 32nd-largest key ----
  if (wv == 0){
    uint32_t vlo = coarse[lane], vhi = coarse[lane + 64];
    #pragma unroll
    for (int d = 1; d < 64; d <<= 1){
      uint32_t t = __shfl_down(vhi, d, 64); if (lane + d < 64) vhi += t;
      t = __shfl_down(vlo, d, 64);          if (lane + d < 64) vlo += t;
    }
    const uint32_t Thi = __shfl(vhi, 0, 64);   // total of hi half
    const uint32_t Slo = vlo + Thi;            // S(c = lane)
    const unsigned long long mhi = __ballot(vhi >= (uint32_t)NP);
    const unsigned long long mlo = __ballot(Slo >= (uint32_t)NP);
    const int cstar = mhi ? (64 + (63 - __clzll(mhi))) : (63 - __clzll(mlo));
    // A = S(cstar+1): count strictly above coarse bin cstar
    const int cn = cstar + 1;
    const uint32_t t1 = __shfl(vhi, (cn - 64) & 63, 64);
    const uint32_t t2 = __shfl(Slo, cn & 63, 64);
    const uint32_t A  = (cn >= 128) ? 0u : ((cn >= 64) ? t1 : t2);
    // fine suffix within coarse bin cstar
    uint32_t f = hist[cstar * 64 + lane];
    #pragma unroll
    for (int d = 1; d < 64; d <<= 1){
      uint32_t t = __shfl_down(f, d, 64); if (lane + d < 64) f += t;
    }
    const unsigned long long mf = __ballot(A + f >= (uint32_t)NP);
    const int lstar = 63 - __clzll(mf);        // exists: C(cstar*64) >= 32
    if (lane == 0) stcut = cstar * 64 + lstar - 2;   // 2-bin safety margin
  }
  __syncthreads();
  const int tcut = stcut;

  // ---- append candidates (all elements in bins >= tcut) ----
  #pragma unroll
  for (int q = 0; q < QP; ++q){
    if ((int)(kreg[q] >> 19) >= tcut){
      const int p = atomicAdd(&scnt, 1);
      if (p < MAXC) candj[p] = (unsigned short)((tid << 2) + q);
    }
  }
  __syncthreads();
  const int M = scnt < MAXC ? scnt : MAXC;

  // ---- exact re-score (bit-identical ocml logf formula) ----
  if (tid < M){
    const int j = candj[tid];
    const int e = b * GRID + j;
    uint32_t o0, o1;
    threefry2x32_k042(0u, (uint32_t)e, o0, o1);
    const float u = u01(o0 ^ o1);
    const float gum  = -logf(-logf(u + EPSF) + EPSF);
    const float prob = a[j] / sum;
    const float se   = logf(prob + EPSF) + gum;
    dkey[tid]  = ((unsigned long long)mono_f32(se) << 32)
               | (uint32_t)(GRID - 1 - j);
    dprob[tid] = prob;
  }
  __syncthreads();

  // ---- exact rank among M candidates; rank < 32 -> emit ----
  if (tid < M){
    const unsigned long long mk = dkey[tid];
    int rank = 0;
    #pragma unroll 4
    for (int c = 0; c < M; ++c) rank += (dkey[c] > mk) ? 1 : 0;
    if (rank < NP){
      const int j   = GRID - 1 - (int)(uint32_t)(mk & 0xFFFFFFFFull);
      const int row = j >> 6, col = j & 63;
      int y0 = row * 32 - 48; y0 = y0 < 0 ? 0 : (y0 > 1920 ? 1920 : y0);
      int x0 = col * 32 - 48; x0 = x0 < 0 ? 0 : (x0 > 1920 ? 1920 : x0);
      gtab[rank] = make_int2(y0, x0);
      if (g == 0) out_attn[b * NP + rank] = dprob[tid];
    }
  }
  __syncthreads();

  // ================= gather: this block's 1/64 slice of its batch ============
  // per batch: rows = 32*3*128 = 12288, each row = 32 float4.
  int t = g * NT + tid;                       // [0, 65536) per iteration step
  #pragma unroll
  for (int it = 0; it < GITER; ++it, t += BPB * NT){
    const int l4   = t & 31;          // float4 within the 128-float row
    const int rowb = t >> 5;          // [0, 12288) within batch
    const int r    = rowb & 127;
    const int tmp  = rowb >> 7;       // n*3 + c, [0, 96)
    const int c    = tmp % 3;
    const int n    = tmp / 3;
    const int2 yx  = gtab[n];         // (y0, x0); x0 multiple of 16 -> aligned
    const size_t off = ((size_t)((b * 3 + c) * HW + yx.x + r)) * HW + (size_t)yx.y;
    const f32x4 v = *reinterpret_cast<const f32x4*>(wsi + off + (size_t)l4 * 4);
    __builtin_nontemporal_store(v, out4 + ((size_t)b * 12288 + rowb) * 32 + l4);
  }
}
} // namespace

extern "C" void kernel_launch(void* const* d_in, const int* in_sizes, int n_in,
                              void* d_out, int out_size, void* d_ws, size_t ws_size,
                              hipStream_t stream) {
  const float* att = (const float*)d_in[2];
  const float* wsi = (const float*)d_in[3];
  float* out       = (float*)d_out;
  float* out_attn  = out + (size_t)B * NP * 3 * PATCH_ * PATCH_;  // 6,291,456

  fused_sample_gather<<<NBLK, NT, 0, stream>>>(att, wsi, out_attn, (f32x4*)out);
}